// Round 11
// baseline (361.724 us; speedup 1.0000x reference)
//
#include <hip/hip_runtime.h>

// B=32, H=W=64, C=384, ws=8, heads=12, hd=32; windows=2048, N=64 tokens.
// Path 1: prep -> qkv_attn (2 win/block, 8 waves=(dh,w,th), full-W resident,
//                 T=2 token-tiles/wave -> 36 LDS reads : 72 MFMA, 3 bars/head)
//              -> proj_gemm. Path 2 fallback: win_attn_fused (r10).
// W LDS layout (fragment-major, r10-verified): half dh at dh*36864B; frag(g,kk,rt,c)
//   at dh*36864 + g*9216 + c*16 + kk*768 + rt*256.

typedef __attribute__((ext_vector_type(8))) short bf16x8;
typedef __attribute__((ext_vector_type(4))) float f32x4;
typedef __attribute__((ext_vector_type(4))) short short4_t;

__device__ __forceinline__ short f2bf(float f) {
    union { float f; unsigned u; } v; v.f = f;
    unsigned r = v.u + 0x7fffu + ((v.u >> 16) & 1u);   // RNE
    return (short)(r >> 16);
}

__device__ __forceinline__ unsigned pk2(float a, float b) {
    return ((unsigned)(unsigned short)f2bf(b) << 16) | (unsigned short)f2bf(a);
}

__device__ __forceinline__ f32x4 mfma16(bf16x8 a, bf16x8 b, f32x4 c) {
    return __builtin_amdgcn_mfma_f32_16x16x32_bf16(a, b, c, 0, 0, 0);
}

__device__ __forceinline__ short4_t pack4(f32x4 v) {
    short4_t s;
    s.x = f2bf(v[0]); s.y = f2bf(v[1]); s.z = f2bf(v[2]); s.w = f2bf(v[3]);
    return s;
}

__device__ __forceinline__ void gload_lds16(const void* g, void* l) {
    __builtin_amdgcn_global_load_lds(
        (const __attribute__((address_space(1))) unsigned int*)g,
        (__attribute__((address_space(3))) unsigned int*)l, 16, 0, 0);
}

__device__ __forceinline__ void drain_vmem() {
    asm volatile("s_waitcnt vmcnt(0)" ::: "memory");
    __builtin_amdgcn_sched_barrier(0);
}

// ---- prep (unchanged from r10): fragment-major QKV weights + wp^T ----
__global__ void prep_weights(const float* __restrict__ wqkv, const float* __restrict__ wproj,
                             short* __restrict__ wq_fm, short* __restrict__ wp_t) {
    const int QKV_ELEMS = 12 * 96 * 384;
    int i = blockIdx.x * 256 + threadIdx.x;
    if (i < QKV_ELEMS) {
        int e    = i & 7;
        int f    = i >> 3;
        int row  = f % 48;
        int kk   = (f / 48) % 12;
        int g    = (f / (48 * 12)) % 4;
        int half = (f / (48 * 12 * 4)) & 1;
        int h    = f / (48 * 12 * 4 * 2);
        int grow = half * 48 + row;
        int k    = kk * 32 + g * 8 + e;
        int col  = (grow >> 5) * 384 + h * 32 + (grow & 31);
        float w = wqkv[k * 1152 + col];
        if (grow < 32) w *= 0.17677669529663687f;
        wq_fm[i] = f2bf(w);
    } else if (i < QKV_ELEMS + 384 * 384) {
        int j = i - QKV_ELEMS;
        int n = j / 384, k = j % 384;
        wp_t[j] = f2bf(wproj[k * 384 + n]);
    }
}

// ================= kernel A: QKV + attention, T=2 per wave ==================
__global__ __launch_bounds__(512, 2)
void qkv_attn(const float* __restrict__ x, const short* __restrict__ wq_fm,
              short* __restrict__ y_sw) {
    __shared__ short Wl[96 * 384];       // 73,728 B full W(h), fragment-major
    __shared__ short k_s[2][64 * 40];    // 10,240 B
    __shared__ short v_t[2][32 * 72];    //  9,216 B
    __shared__ short ps[2][64 * 72];     // 18,432 B   -> 111,616 B, 1 block/CU

    const int tid   = threadIdx.x;
    const int lane  = tid & 63;
    const int wid   = tid >> 6;      // 0..7
    const int col16 = lane & 15;
    const int kgrp  = lane >> 4;
    const int dh    = wid >> 2;      // W row-half: 0 = Q0,Q1,K0; 1 = K1,V0,V1
    const int w     = (wid >> 1) & 1;// window in block
    const int th    = wid & 1;       // token half (tokens th*32..+31)
    const int quad  = dh * 2 + th;   // PV-role quad within window w

    const int win = blockIdx.x * 2 + w;
    const int b = win >> 6, wi = win & 63, whr = wi >> 3, wwc = wi & 7;
    const float* xbase = x + (((b * 64) + whr * 8) * 64 + wwc * 8) * 384;

    // per-lane W base for this wave's 3 row-tiles
    const char* Wb = (const char*)Wl + dh * 36864 + kgrp * 9216 + col16 * 16;

    // ---- DMA W(0): all waves, 9 chunks each ----
    for (int i = wid; i < 72; i += 8)
        gload_lds16(wq_fm + i * 512 + lane * 8, &Wl[i * 512]);

    // ---- x: 2 token-tiles -> registers (96 VGPR) ----
    bf16x8 xf[2][12];
#pragma unroll
    for (int nt = 0; nt < 2; ++nt) {
        int t = th * 32 + nt * 16 + col16;
        const float* xr = xbase + ((t >> 3) * 64 + (t & 7)) * 384;
#pragma unroll
        for (int kk = 0; kk < 12; ++kk) {
            const float* p0 = xr + kk * 32 + kgrp * 8;
            float4 a = *reinterpret_cast<const float4*>(p0);
            float4 c = *reinterpret_cast<const float4*>(p0 + 4);
            bf16x8 f;
            f[0] = f2bf(a.x); f[1] = f2bf(a.y); f[2] = f2bf(a.z); f[3] = f2bf(a.w);
            f[4] = f2bf(c.x); f[5] = f2bf(c.y); f[6] = f2bf(c.z); f[7] = f2bf(c.w);
            xf[nt][kk] = f;
        }
    }

    // y addressing (PV role): token g
    const int g = win * 64 + quad * 16 + col16;
    const int mtile = g >> 7, yrow = g & 127;
    char* ybase = (char*)y_sw + (size_t)mtile * 98304 + (size_t)yrow * 128;

    for (int h = 0; h < 12; ++h) {
        drain_vmem();      // own W-DMA chunks (and y stores) landed
        __syncthreads();   // BAR1: W(h) visible; k_s/v_t/ps free (prev PV done)

        // ---- QKV: 3 row-tiles x 2 tok-tiles x 12 kk = 72 MFMA, 36 reads ----
        f32x4 acc[3][2];
#pragma unroll
        for (int i = 0; i < 3; ++i)
#pragma unroll
            for (int j = 0; j < 2; ++j) acc[i][j] = (f32x4){0.f, 0.f, 0.f, 0.f};

        if (dh == 0) {       // Q d0, Q d1, K d0 : all mfma(W, x) -> D[dim][tok]
#pragma unroll
            for (int kk = 0; kk < 12; ++kk) {
                bf16x8 wf0 = *reinterpret_cast<const bf16x8*>(Wb + kk * 768);
                bf16x8 wf1 = *reinterpret_cast<const bf16x8*>(Wb + kk * 768 + 256);
                bf16x8 wf2 = *reinterpret_cast<const bf16x8*>(Wb + kk * 768 + 512);
#pragma unroll
                for (int nt = 0; nt < 2; ++nt) {
                    acc[0][nt] = mfma16(wf0, xf[nt][kk], acc[0][nt]);
                    acc[1][nt] = mfma16(wf1, xf[nt][kk], acc[1][nt]);
                    acc[2][nt] = mfma16(wf2, xf[nt][kk], acc[2][nt]);
                }
            }
        } else {             // K d1: mfma(W,x); V d0,d1: mfma(x,W) -> D[tok][dim]
#pragma unroll
            for (int kk = 0; kk < 12; ++kk) {
                bf16x8 wfK  = *reinterpret_cast<const bf16x8*>(Wb + kk * 768);
                bf16x8 wfV0 = *reinterpret_cast<const bf16x8*>(Wb + kk * 768 + 256);
                bf16x8 wfV1 = *reinterpret_cast<const bf16x8*>(Wb + kk * 768 + 512);
#pragma unroll
                for (int nt = 0; nt < 2; ++nt) {
                    acc[0][nt] = mfma16(wfK, xf[nt][kk], acc[0][nt]);
                    acc[1][nt] = mfma16(xf[nt][kk], wfV0, acc[1][nt]);
                    acc[2][nt] = mfma16(xf[nt][kk], wfV1, acc[2][nt]);
                }
            }
        }

        // ---- scatters + Q relayout ----
        bf16x8 qa[2];
        if (dh == 0) {
            // Q relayout per tok-tile (r4/r5-verified): acc[0]=dims0-15, acc[1]=16-31
#pragma unroll
            for (int nt = 0; nt < 2; ++nt) {
                unsigned A0 = pk2(acc[0][nt][0], acc[0][nt][1]);
                unsigned A1 = pk2(acc[0][nt][2], acc[0][nt][3]);
                unsigned B0 = pk2(acc[1][nt][0], acc[1][nt][1]);
                unsigned B1 = pk2(acc[1][nt][2], acc[1][nt][3]);
                int s0 = ((kgrp & 1) * 2) * 16 + col16;
                int a0 = __shfl((int)A0, s0, 64),      a1 = __shfl((int)A1, s0, 64);
                int a2 = __shfl((int)A0, s0 + 16, 64), a3 = __shfl((int)A1, s0 + 16, 64);
                int b0 = __shfl((int)B0, s0, 64),      b1 = __shfl((int)B1, s0, 64);
                int b2 = __shfl((int)B0, s0 + 16, 64), b3 = __shfl((int)B1, s0 + 16, 64);
                union { int i[4]; bf16x8 v; } qu;
                const bool loHalf = (kgrp < 2);
                qu.i[0] = loHalf ? a0 : b0;
                qu.i[1] = loHalf ? a1 : b1;
                qu.i[2] = loHalf ? a2 : b2;
                qu.i[3] = loHalf ? a3 : b3;
                qa[nt] = qu.v;
            }
            // K dims 0..15
#pragma unroll
            for (int nt = 0; nt < 2; ++nt)
                *reinterpret_cast<short4_t*>(
                    &k_s[w][(th * 32 + nt * 16 + col16) * 40 + kgrp * 4]) = pack4(acc[2][nt]);
        } else {
            // K dims 16..31
#pragma unroll
            for (int nt = 0; nt < 2; ++nt)
                *reinterpret_cast<short4_t*>(
                    &k_s[w][(th * 32 + nt * 16 + col16) * 40 + 16 + kgrp * 4]) = pack4(acc[0][nt]);
            // V: D[tok][dim] -> v_t[dim][tok]
#pragma unroll
            for (int vt = 0; vt < 2; ++vt)
#pragma unroll
                for (int nt = 0; nt < 2; ++nt)
                    *reinterpret_cast<short4_t*>(
                        &v_t[w][(vt * 16 + col16) * 72 + th * 32 + nt * 16 + kgrp * 4]) =
                        pack4(acc[1 + vt][nt]);
        }

        __syncthreads();   // BAR2: K/V visible; Wl consumed

        // ---- DMA W(h+1) (all waves; lands by next BAR1's drain) ----
        if (h < 11) {
            const short* src = wq_fm + (h + 1) * 36864;
            for (int i = wid; i < 72; i += 8)
                gload_lds16(src + i * 512 + lane * 8, &Wl[i * 512]);
        }

        if (dh == 0) {
            // ---- scores SWAPPED: sc[nt][kt] = mfma(K,Q); lane owns q-row 16 vals ----
            bf16x8 kf[4];
#pragma unroll
            for (int kt = 0; kt < 4; ++kt)
                kf[kt] = *reinterpret_cast<const bf16x8*>(
                    &k_s[w][(kt * 16 + col16) * 40 + kgrp * 8]);
#pragma unroll
            for (int nt = 0; nt < 2; ++nt) {
                f32x4 sc[4];
#pragma unroll
                for (int kt = 0; kt < 4; ++kt) {
                    f32x4 z = (f32x4){0.f, 0.f, 0.f, 0.f};
                    sc[kt] = mfma16(kf[kt], qa[nt], z);
                }
                float m = sc[0][0];
#pragma unroll
                for (int kt = 0; kt < 4; ++kt)
#pragma unroll
                    for (int r = 0; r < 4; ++r) m = fmaxf(m, sc[kt][r]);
                m = fmaxf(m, __shfl_xor(m, 16, 64));
                m = fmaxf(m, __shfl_xor(m, 32, 64));
                float s = 0.f;
#pragma unroll
                for (int kt = 0; kt < 4; ++kt)
#pragma unroll
                    for (int r = 0; r < 4; ++r) {
                        sc[kt][r] = __expf(sc[kt][r] - m);
                        s += sc[kt][r];
                    }
                s += __shfl_xor(s, 16, 64);
                s += __shfl_xor(s, 32, 64);
                float inv = 1.0f / s;
                int prow = th * 32 + nt * 16 + col16;
#pragma unroll
                for (int kt = 0; kt < 4; ++kt) {
                    f32x4 pv;
                    pv[0] = sc[kt][0] * inv; pv[1] = sc[kt][1] * inv;
                    pv[2] = sc[kt][2] * inv; pv[3] = sc[kt][3] * inv;
                    *reinterpret_cast<short4_t*>(
                        &ps[w][prow * 72 + kt * 16 + kgrp * 4]) = pack4(pv);
                }
            }
        }

        __syncthreads();   // BAR3: P visible

        // ---- PV (all 8 waves): (window w, quad); mfma(V^T, P) -> D[dim][q] ----
        f32x4 o2[2];
        o2[0] = (f32x4){0.f, 0.f, 0.f, 0.f};
        o2[1] = (f32x4){0.f, 0.f, 0.f, 0.f};
#pragma unroll
        for (int kt = 0; kt < 2; ++kt) {
            bf16x8 pb = *reinterpret_cast<const bf16x8*>(
                &ps[w][(quad * 16 + col16) * 72 + kt * 32 + kgrp * 8]);
#pragma unroll
            for (int d = 0; d < 2; ++d) {
                bf16x8 va = *reinterpret_cast<const bf16x8*>(
                    &v_t[w][(d * 16 + col16) * 72 + kt * 32 + kgrp * 8]);
                o2[d] = mfma16(va, pb, o2[d]);
            }
        }
        // ---- y write (swizzled proj-A image) ----
#pragma unroll
        for (int d = 0; d < 2; ++d) {
            int c0 = h * 32 + d * 16 + kgrp * 4;
            int kchunk = c0 >> 6;
            int koff = (2 * (c0 & 63)) ^ ((yrow & 7) << 4);
            *reinterpret_cast<short4_t*>(ybase + kchunk * 16384 + koff) = pack4(o2[d]);
        }
    }
}

// ================= kernel B: out = y @ wp + bias, window_reverse (r10) ===========
__global__ __launch_bounds__(256)
void proj_gemm(const short* __restrict__ y_sw, const short* __restrict__ wp_t,
               const float* __restrict__ b_proj, float* __restrict__ out) {
    __shared__ short At[2][128 * 64];

    const int tid = threadIdx.x, lane = tid & 63, wv = tid >> 6;
    const int col16 = lane & 15, kgrp = lane >> 4;
    const int wm = wv >> 1, wn = wv & 1;
    const int mtile = blockIdx.x;
    const int nblk  = blockIdx.y;

    const short* asrc = y_sw + (size_t)mtile * 6 * 128 * 64;

    for (int i = wv; i < 16; i += 4)
        gload_lds16(asrc + i * 512 + lane * 8, &At[0][i * 512]);

    const short* bptr[4];
#pragma unroll
    for (int nt = 0; nt < 4; ++nt)
        bptr[nt] = wp_t + (size_t)(nblk * 128 + wn * 64 + nt * 16 + col16) * 384;

    f32x4 acc[4][4];
#pragma unroll
    for (int i = 0; i < 4; ++i)
#pragma unroll
        for (int j = 0; j < 4; ++j) acc[i][j] = (f32x4){0.f, 0.f, 0.f, 0.f};

    int cur = 0;
    for (int ks = 0; ks < 6; ++ks) {
        drain_vmem();
        __syncthreads();
        if (ks < 5) {
            const short* src = asrc + (ks + 1) * (128 * 64);
            for (int i = wv; i < 16; i += 4)
                gload_lds16(src + i * 512 + lane * 8, &At[cur ^ 1][i * 512]);
        }
#pragma unroll
        for (int kk = 0; kk < 2; ++kk) {
            const int kbyte = kk * 64 + kgrp * 16;
            bf16x8 af[4];
#pragma unroll
            for (int mt = 0; mt < 4; ++mt) {
                const int r = wm * 64 + mt * 16 + col16;
                af[mt] = *reinterpret_cast<const bf16x8*>(
                    (const char*)At[cur] + r * 128 + (kbyte ^ ((r & 7) << 4)));
            }
#pragma unroll
            for (int nt = 0; nt < 4; ++nt) {
                bf16x8 bf = *reinterpret_cast<const bf16x8*>(bptr[nt] + ks * 64 + kk * 32 + kgrp * 8);
#pragma unroll
                for (int mt = 0; mt < 4; ++mt)
                    acc[mt][nt] = mfma16(af[mt], bf, acc[mt][nt]);
            }
        }
        cur ^= 1;
    }

#pragma unroll
    for (int nt = 0; nt < 4; ++nt) {
        int c = nblk * 128 + wn * 64 + nt * 16 + col16;
        float bias = b_proj[c];
#pragma unroll
        for (int mt = 0; mt < 4; ++mt) {
#pragma unroll
            for (int r = 0; r < 4; ++r) {
                int gg = mtile * 128 + wm * 64 + mt * 16 + kgrp * 4 + r;
                int win = gg >> 6, t = gg & 63;
                int b = win >> 6, whr = (win >> 3) & 7, wwc = win & 7;
                int orow = (b * 64 + whr * 8 + (t >> 3)) * 64 + wwc * 8 + (t & 7);
                out[(size_t)orow * 384 + c] = acc[mt][nt][r] + bias;
            }
        }
    }
}

// ================= Path 2 fallback (r10, fragment-major W) =======================
__global__ __launch_bounds__(512, 2)
void win_attn_fused(const float* __restrict__ x, const short* __restrict__ wq_fm,
                    const short* __restrict__ wp_t, const float* __restrict__ b_proj,
                    float* __restrict__ out) {
    __shared__ short Wl[96 * 384];
    __shared__ short q_s[2][64 * 40];
    __shared__ short k_s[2][64 * 40];
    __shared__ short v_t[2][32 * 72];
    __shared__ short ps[2][64 * 72];

    const int tid   = threadIdx.x;
    const int lane  = tid & 63;
    const int wv    = tid >> 6;
    const int col16 = lane & 15;
    const int kgrp  = lane >> 4;
    const int wwin  = wv >> 2;
    const int q4    = wv & 3;
    const int wm    = q4 >> 1, wn = q4 & 1;

    const int win = blockIdx.x * 2 + wwin;
    const int b = win >> 6, wi = win & 63, whr = wi >> 3, wwc = wi & 7;
    const float* xbase = x + (((b * 64) + whr * 8) * 64 + wwc * 8) * 384;

    const char* Wb = (const char*)Wl + kgrp * 9216 + col16 * 16;

    for (int i = 0; i < 9; ++i) {
        int chunk = wv * 9 + i;
        gload_lds16(wq_fm + chunk * 512 + lane * 8, &Wl[chunk * 512]);
    }
    bf16x8 xf[12];
    {
        int t = q4 * 16 + col16;
        const float* xr = xbase + ((t >> 3) * 64 + (t & 7)) * 384;
#pragma unroll
        for (int kk = 0; kk < 12; ++kk) {
            const float* p0 = xr + kk * 32 + kgrp * 8;
            float4 a = *reinterpret_cast<const float4*>(p0);
            float4 c = *reinterpret_cast<const float4*>(p0 + 4);
            bf16x8 f;
            f[0] = f2bf(a.x); f[1] = f2bf(a.y); f[2] = f2bf(a.z); f[3] = f2bf(a.w);
            f[4] = f2bf(c.x); f[5] = f2bf(c.y); f[6] = f2bf(c.z); f[7] = f2bf(c.w);
            xf[kk] = f;
        }
    }
    f32x4 pacc[2][12];
#pragma unroll
    for (int i = 0; i < 2; ++i)
#pragma unroll
        for (int j = 0; j < 12; ++j) pacc[i][j] = (f32x4){0.f, 0.f, 0.f, 0.f};

    for (int h = 0; h < 12; ++h) {
        drain_vmem();
        __syncthreads();
        f32x4 acc[6];
#pragma unroll
        for (int i = 0; i < 6; ++i) acc[i] = (f32x4){0.f, 0.f, 0.f, 0.f};
#pragma unroll
        for (int kk = 0; kk < 12; ++kk) {
#pragma unroll
            for (int rd = 0; rd < 6; ++rd) {
                const bf16x8 wf = *reinterpret_cast<const bf16x8*>(
                    Wb + (rd / 3) * 36864 + kk * 768 + (rd % 3) * 256);
                if (rd < 4) acc[rd] = mfma16(wf, xf[kk], acc[rd]);
                else        acc[rd] = mfma16(xf[kk], wf, acc[rd]);
            }
        }
#pragma unroll
        for (int rd = 0; rd < 4; ++rd) {
            short* dst = (rd < 2) ? q_s[wwin] : k_s[wwin];
            *reinterpret_cast<short4_t*>(
                &dst[(q4 * 16 + col16) * 40 + (rd & 1) * 16 + kgrp * 4]) = pack4(acc[rd]);
        }
#pragma unroll
        for (int d = 0; d < 2; ++d)
            *reinterpret_cast<short4_t*>(
                &v_t[wwin][(d * 16 + col16) * 72 + q4 * 16 + kgrp * 4]) = pack4(acc[4 + d]);

        __syncthreads();
        if (h < 11) {
            const short* src = wq_fm + (h + 1) * 36864;
            for (int i = 0; i < 9; ++i) {
                int chunk = wv * 9 + i;
                gload_lds16(src + chunk * 512 + lane * 8, &Wl[chunk * 512]);
            }
        }
        bf16x8 qa = *reinterpret_cast<const bf16x8*>(
            &q_s[wwin][(q4 * 16 + col16) * 40 + kgrp * 8]);
        f32x4 sc[4];
#pragma unroll
        for (int nt = 0; nt < 4; ++nt) {
            bf16x8 kf = *reinterpret_cast<const bf16x8*>(
                &k_s[wwin][(nt * 16 + col16) * 40 + kgrp * 8]);
            f32x4 z = (f32x4){0.f, 0.f, 0.f, 0.f};
            sc[nt] = mfma16(qa, kf, z);
        }
        float mx[4], sm[4], p[4][4];
#pragma unroll
        for (int r = 0; r < 4; ++r)
            mx[r] = fmaxf(fmaxf(sc[0][r], sc[1][r]), fmaxf(sc[2][r], sc[3][r]));
#pragma unroll
        for (int d = 1; d < 16; d <<= 1)
#pragma unroll
            for (int r = 0; r < 4; ++r) mx[r] = fmaxf(mx[r], __shfl_xor(mx[r], d, 16));
#pragma unroll
        for (int r = 0; r < 4; ++r) {
            sm[r] = 0.f;
#pragma unroll
            for (int nt = 0; nt < 4; ++nt) { p[nt][r] = __expf(sc[nt][r] - mx[r]); sm[r] += p[nt][r]; }
        }
#pragma unroll
        for (int d = 1; d < 16; d <<= 1)
#pragma unroll
            for (int r = 0; r < 4; ++r) sm[r] += __shfl_xor(sm[r], d, 16);
#pragma unroll
        for (int r = 0; r < 4; ++r) {
            float inv = 1.0f / sm[r];
            int prow = q4 * 16 + kgrp * 4 + r;
#pragma unroll
            for (int nt = 0; nt < 4; ++nt)
                ps[wwin][prow * 72 + nt * 16 + col16] = f2bf(p[nt][r] * inv);
        }
        f32x4 o2[2];
        o2[0] = (f32x4){0.f, 0.f, 0.f, 0.f};
        o2[1] = (f32x4){0.f, 0.f, 0.f, 0.f};
#pragma unroll
        for (int kt = 0; kt < 2; ++kt) {
            bf16x8 pb = *reinterpret_cast<const bf16x8*>(
                &ps[wwin][(q4 * 16 + col16) * 72 + kt * 32 + kgrp * 8]);
#pragma unroll
            for (int d = 0; d < 2; ++d) {
                bf16x8 va = *reinterpret_cast<const bf16x8*>(
                    &v_t[wwin][(d * 16 + col16) * 72 + kt * 32 + kgrp * 8]);
                o2[d] = mfma16(va, pb, o2[d]);
            }
        }
#pragma unroll
        for (int d = 0; d < 2; ++d)
            *reinterpret_cast<short4_t*>(
                &ps[wwin][(q4 * 16 + col16) * 72 + d * 16 + kgrp * 4]) = pack4(o2[d]);
        __syncthreads();
#pragma unroll
        for (int mt = 0; mt < 2; ++mt) {
            bf16x8 ya = *reinterpret_cast<const bf16x8*>(
                &ps[wwin][(wm * 32 + mt * 16 + col16) * 72 + kgrp * 8]);
#pragma unroll
            for (int nt = 0; nt < 12; ++nt) {
                bf16x8 wb = *reinterpret_cast<const bf16x8*>(
                    &wp_t[(wn * 192 + nt * 16 + col16) * 384 + h * 32 + kgrp * 8]);
                pacc[mt][nt] = mfma16(ya, wb, pacc[mt][nt]);
            }
        }
    }
#pragma unroll
    for (int nt = 0; nt < 12; ++nt) {
        int c = wn * 192 + nt * 16 + col16;
        float bias = b_proj[c];
#pragma unroll
        for (int mt = 0; mt < 2; ++mt) {
#pragma unroll
            for (int r = 0; r < 4; ++r) {
                int token = wm * 32 + mt * 16 + kgrp * 4 + r;
                int hh = whr * 8 + (token >> 3);
                int ww2 = wwc * 8 + (token & 7);
                out[(((b * 64) + hh) * 64 + ww2) * 384 + c] = pacc[mt][nt][r] + bias;
            }
        }
    }
}

extern "C" void kernel_launch(void* const* d_in, const int* in_sizes, int n_in,
                              void* d_out, int out_size, void* d_ws, size_t ws_size,
                              hipStream_t stream) {
    const float* x     = (const float*)d_in[0];
    const float* wqkv  = (const float*)d_in[1];
    const float* wproj = (const float*)d_in[2];
    const float* bproj = (const float*)d_in[3];

    short* wq_fm = (short*)d_ws;                  // 884,736 B (fragment-major)
    short* wp_t  = wq_fm + 12 * 96 * 384;         // 294,912 B
    short* y_sw  = wp_t + 384 * 384;              // 100,663,296 B (path 1 only)
    const size_t need = (size_t)(12 * 96 * 384 + 384 * 384) * 2 + (size_t)1024 * 6 * 128 * 128;

    prep_weights<<<2304, 256, 0, stream>>>(wqkv, wproj, wq_fm, wp_t);
    if (ws_size >= need) {
        qkv_attn<<<1024, 512, 0, stream>>>(x, wq_fm, y_sw);
        proj_gemm<<<dim3(1024, 3), 256, 0, stream>>>(y_sw, wp_t, bproj, (float*)d_out);
    } else {
        win_attn_fused<<<1024, 512, 0, stream>>>(x, wq_fm, wp_t, bproj, (float*)d_out);
    }
}